// Round 1
// baseline (310.540 us; speedup 1.0000x reference)
//
#include <hip/hip_runtime.h>

typedef unsigned short u16;
typedef __attribute__((ext_vector_type(8))) short bfrag;   // 8 x bf16
typedef __attribute__((ext_vector_type(4))) float f32x4;

#define SROW 1032   // padded LDS row stride (bf16 elems) for the 1024-wide s history

__device__ __forceinline__ u16 f2bf(float x) {
    unsigned int v = __float_as_uint(x);
    return (u16)((v + 0x7FFFu + ((v >> 16) & 1u)) >> 16);   // RNE
}

__device__ __forceinline__ float fast_tanh(float x) {
    float ax = __builtin_fabsf(x);
    float e  = __builtin_amdgcn_exp2f(ax * -2.885390081777927f);   // e^(-2|x|)
    float r  = (1.0f - e) * __builtin_amdgcn_rcpf(1.0f + e);
    return __builtin_copysignf(r, x);
}

// ---------------- prologue: bf16 conversions + diag-block transpose ----------------
// granule = 4 elements. Segments:
//   Bs   : [0,      262144)   1024x1024, tril(k=-1) masked
//   B_w  : [262144, 294912)   1024x128
//   Ds_w : [294912, 327680)   128x1024
//   D_w  : [327680, 331776)   128x128
//   diagT: [331776, 339968)   32 blocks of 32x32 f32, transposed, strict-lower
__global__ void ren_prologue(const float* __restrict__ Bs, const float* __restrict__ Bw,
                             const float* __restrict__ Ds, const float* __restrict__ Dw,
                             u16* __restrict__ bs16, u16* __restrict__ bw16,
                             u16* __restrict__ ds16, u16* __restrict__ dw16,
                             float* __restrict__ diagT)
{
    const int g = blockIdx.x * 256 + threadIdx.x;
    if (g < 262144) {
        const int idx = g * 4;
        const int i = idx >> 10, j = idx & 1023;
        const float4 v = *reinterpret_cast<const float4*>(Bs + idx);
        u16 o[4];
        o[0] = (j + 0 < i) ? f2bf(v.x) : (u16)0;
        o[1] = (j + 1 < i) ? f2bf(v.y) : (u16)0;
        o[2] = (j + 2 < i) ? f2bf(v.z) : (u16)0;
        o[3] = (j + 3 < i) ? f2bf(v.w) : (u16)0;
        *reinterpret_cast<uint2*>(bs16 + idx) = *reinterpret_cast<const uint2*>(o);
    } else if (g < 294912) {
        const int idx = (g - 262144) * 4;
        const float4 v = *reinterpret_cast<const float4*>(Bw + idx);
        u16 o[4] = { f2bf(v.x), f2bf(v.y), f2bf(v.z), f2bf(v.w) };
        *reinterpret_cast<uint2*>(bw16 + idx) = *reinterpret_cast<const uint2*>(o);
    } else if (g < 327680) {
        const int idx = (g - 294912) * 4;
        const float4 v = *reinterpret_cast<const float4*>(Ds + idx);
        u16 o[4] = { f2bf(v.x), f2bf(v.y), f2bf(v.z), f2bf(v.w) };
        *reinterpret_cast<uint2*>(ds16 + idx) = *reinterpret_cast<const uint2*>(o);
    } else if (g < 331776) {
        const int idx = (g - 327680) * 4;
        const float4 v = *reinterpret_cast<const float4*>(Dw + idx);
        u16 o[4] = { f2bf(v.x), f2bf(v.y), f2bf(v.z), f2bf(v.w) };
        *reinterpret_cast<uint2*>(dw16 + idx) = *reinterpret_cast<const uint2*>(o);
    } else if (g < 339968) {
        const int lin0 = (g - 331776) * 4;
        #pragma unroll
        for (int t = 0; t < 4; ++t) {
            const int l = lin0 + t;
            const int bb = l >> 10, rem = l & 1023, i = rem >> 5, j = rem & 31;
            // diagT[b][i][j] = Bs[32b+j, 32b+i] for j>i (update weight from unit i to unit j)
            diagT[l] = (j > i) ? Bs[(size_t)(bb * 32 + j) * 1024 + (bb * 32 + i)] : 0.0f;
        }
    }
}

// ---------------- main: blocked triangular recurrence + output GEMM ----------------
__global__ __launch_bounds__(256) void ren_main(
    const float* __restrict__ u,
    const u16* __restrict__ bs16, const u16* __restrict__ bw16,
    const u16* __restrict__ ds16, const u16* __restrict__ dw16,
    const float* __restrict__ diagT,
    float* __restrict__ out)
{
    __shared__ __align__(16) u16  sh_S[32 * SROW];   // s history, bf16 [32 rows][1024+pad]
    __shared__ float sh_acc[32 * 33];                // pre-activation exchange tile

    const int tid  = threadIdx.x;
    const int wave = tid >> 6;
    const int lane = tid & 63;
    const int mt   = wave >> 1;            // m-tile (batch rows 16*mt..)
    const int ntw  = wave & 1;             // n-tile (hid cols 16*ntw.. within block)
    const int lr   = lane & 15;
    const int lk8  = (lane >> 4) << 3;     // k offset of this lane's 8 contiguous elems
    const int row0 = blockIdx.x << 5;      // 32 batch rows per workgroup

    // u A-fragments for this wave's 16 batch rows (k = 0..127), kept in registers
    bfrag fu[4];
    {
        const float* up = u + (size_t)(row0 + mt * 16 + lr) * 128 + lk8;
        #pragma unroll
        for (int kk = 0; kk < 4; ++kk) {
            float4 a = *reinterpret_cast<const float4*>(up + kk * 32);
            float4 c = *reinterpret_cast<const float4*>(up + kk * 32 + 4);
            bfrag f;
            f[0] = (short)f2bf(a.x); f[1] = (short)f2bf(a.y);
            f[2] = (short)f2bf(a.z); f[3] = (short)f2bf(a.w);
            f[4] = (short)f2bf(c.x); f[5] = (short)f2bf(c.y);
            f[6] = (short)f2bf(c.z); f[7] = (short)f2bf(c.w);
            fu[kk] = f;
        }
    }

    for (int b = 0; b < 32; ++b) {
        // ---- GEMM phase: acc[32,32] = u @ B_w[blk]^T + s_hist @ Bs[blk, :32b]^T ----
        f32x4 acc = {0.f, 0.f, 0.f, 0.f};
        const int ng = (b << 5) + ntw * 16 + lr;       // global hid unit (weight row)

        const u16* bwp = bw16 + ng * 128 + lk8;
        #pragma unroll
        for (int kk = 0; kk < 4; ++kk) {
            bfrag bf = *reinterpret_cast<const bfrag*>(bwp + kk * 32);
            acc = __builtin_amdgcn_mfma_f32_16x16x32_bf16(fu[kk], bf, acc, 0, 0, 0);
        }

        const u16* bsp = bs16 + (size_t)ng * 1024 + lk8;
        const u16* ssp = sh_S + (mt * 16 + lr) * SROW + lk8;
        #pragma unroll 4
        for (int kc = 0; kc < b; ++kc) {
            bfrag af = *reinterpret_cast<const bfrag*>(ssp + kc * 32);
            bfrag bf = *reinterpret_cast<const bfrag*>(bsp + kc * 32);
            acc = __builtin_amdgcn_mfma_f32_16x16x32_bf16(af, bf, acc, 0, 0, 0);
        }

        {   // C/D layout: col = lane&15, row = (lane>>4)*4 + reg
            const int m = mt * 16 + ((lane >> 4) << 2);
            const int c = ntw * 16 + lr;
            #pragma unroll
            for (int rr = 0; rr < 4; ++rr)
                sh_acc[(m + rr) * 33 + c] = acc[rr];
        }
        __syncthreads();

        // ---- serial phase: 32 in-block steps, thread r owns batch row r ----
        if (tid < 32) {
            float part[32];
            #pragma unroll
            for (int j = 0; j < 32; ++j) part[j] = sh_acc[tid * 33 + j];
            const float* dT = diagT + (b << 10);       // wave-uniform -> scalar loads
            u16* srow = sh_S + tid * SROW + (b << 5);
            #pragma unroll
            for (int i = 0; i < 32; ++i) {
                float s = fast_tanh(part[i]);
                srow[i] = f2bf(s);
                #pragma unroll
                for (int j = i + 1; j < 32; ++j)
                    part[j] = __builtin_fmaf(dT[i * 32 + j], s, part[j]);
            }
        }
        __syncthreads();
    }

    // ---- epilogue: y = s @ Ds_w^T + u @ D_w^T  (32 x 128 per workgroup) ----
    f32x4 accy[4];
    #pragma unroll
    for (int t = 0; t < 4; ++t) accy[t] = (f32x4){0.f, 0.f, 0.f, 0.f};

    const u16* ssp = sh_S + (mt * 16 + lr) * SROW + lk8;
    #pragma unroll 2
    for (int kc = 0; kc < 32; ++kc) {
        bfrag af = *reinterpret_cast<const bfrag*>(ssp + (kc << 5));
        #pragma unroll
        for (int t = 0; t < 4; ++t) {
            const int n = ((ntw << 2) + t) * 16 + lr;
            bfrag bf = *reinterpret_cast<const bfrag*>(ds16 + (size_t)n * 1024 + (kc << 5) + lk8);
            accy[t] = __builtin_amdgcn_mfma_f32_16x16x32_bf16(af, bf, accy[t], 0, 0, 0);
        }
    }
    #pragma unroll
    for (int kk = 0; kk < 4; ++kk) {
        #pragma unroll
        for (int t = 0; t < 4; ++t) {
            const int n = ((ntw << 2) + t) * 16 + lr;
            bfrag bf = *reinterpret_cast<const bfrag*>(dw16 + n * 128 + (kk << 5) + lk8);
            accy[t] = __builtin_amdgcn_mfma_f32_16x16x32_bf16(fu[kk], bf, accy[t], 0, 0, 0);
        }
    }

    {
        const int mbase = row0 + mt * 16 + ((lane >> 4) << 2);
        #pragma unroll
        for (int t = 0; t < 4; ++t) {
            const int n = ((ntw << 2) + t) * 16 + lr;
            #pragma unroll
            for (int rr = 0; rr < 4; ++rr)
                out[(size_t)(mbase + rr) * 128 + n] = accy[t][rr];
        }
    }
}

extern "C" void kernel_launch(void* const* d_in, const int* in_sizes, int n_in,
                              void* d_out, int out_size, void* d_ws, size_t ws_size,
                              hipStream_t stream)
{
    const float* u  = (const float*)d_in[0];   // [8192,128]
    const float* Bw = (const float*)d_in[1];   // [1024,128]
    const float* Bs = (const float*)d_in[2];   // [1024,1024]
    const float* Ds = (const float*)d_in[3];   // [128,1024]
    const float* Dw = (const float*)d_in[4];   // [128,128]
    float* out = (float*)d_out;

    u16* bs16 = (u16*)d_ws;                    // 1024*1024 bf16
    u16* bw16 = bs16 + 1024 * 1024;            // 1024*128
    u16* ds16 = bw16 + 1024 * 128;             // 128*1024
    u16* dw16 = ds16 + 128 * 1024;             // 128*128
    float* diagT = (float*)(dw16 + 128 * 128); // 32*32*32 f32 (byte offset 2,654,208: 16B aligned)

    ren_prologue<<<1328, 256, 0, stream>>>(Bs, Bw, Ds, Dw, bs16, bw16, ds16, dw16, diagT);
    ren_main<<<256, 256, 0, stream>>>(u, bs16, bw16, ds16, dw16, diagT, out);
}

// Round 2
// 258.551 us; speedup vs baseline: 1.2011x; 1.2011x over previous
//
#include <hip/hip_runtime.h>

typedef unsigned short u16;
typedef __attribute__((ext_vector_type(8))) short bfrag;   // 8 x bf16
typedef __attribute__((ext_vector_type(4))) float f32x4;

#define SROW 1032   // padded LDS row stride (bf16 elems) for the 1024-wide s history

__device__ __forceinline__ u16 f2bf(float x) {
    unsigned int v = __float_as_uint(x);
    return (u16)((v + 0x7FFFu + ((v >> 16) & 1u)) >> 16);   // RNE
}

__device__ __forceinline__ float fast_tanh(float x) {
    float ax = __builtin_fabsf(x);
    float e  = __builtin_amdgcn_exp2f(ax * -2.885390081777927f);   // e^(-2|x|)
    float r  = (1.0f - e) * __builtin_amdgcn_rcpf(1.0f + e);
    return __builtin_copysignf(r, x);
}

// ---------------- prologue: bf16 conversions + diag-block transpose ----------------
__global__ void ren_prologue(const float* __restrict__ Bs, const float* __restrict__ Bw,
                             const float* __restrict__ Ds, const float* __restrict__ Dw,
                             u16* __restrict__ bs16, u16* __restrict__ bw16,
                             u16* __restrict__ ds16, u16* __restrict__ dw16,
                             float* __restrict__ diagT)
{
    const int g = blockIdx.x * 256 + threadIdx.x;
    if (g < 262144) {
        const int idx = g * 4;
        const int i = idx >> 10, j = idx & 1023;
        const float4 v = *reinterpret_cast<const float4*>(Bs + idx);
        u16 o[4];
        o[0] = (j + 0 < i) ? f2bf(v.x) : (u16)0;
        o[1] = (j + 1 < i) ? f2bf(v.y) : (u16)0;
        o[2] = (j + 2 < i) ? f2bf(v.z) : (u16)0;
        o[3] = (j + 3 < i) ? f2bf(v.w) : (u16)0;
        *reinterpret_cast<uint2*>(bs16 + idx) = *reinterpret_cast<const uint2*>(o);
    } else if (g < 294912) {
        const int idx = (g - 262144) * 4;
        const float4 v = *reinterpret_cast<const float4*>(Bw + idx);
        u16 o[4] = { f2bf(v.x), f2bf(v.y), f2bf(v.z), f2bf(v.w) };
        *reinterpret_cast<uint2*>(bw16 + idx) = *reinterpret_cast<const uint2*>(o);
    } else if (g < 327680) {
        const int idx = (g - 294912) * 4;
        const float4 v = *reinterpret_cast<const float4*>(Ds + idx);
        u16 o[4] = { f2bf(v.x), f2bf(v.y), f2bf(v.z), f2bf(v.w) };
        *reinterpret_cast<uint2*>(ds16 + idx) = *reinterpret_cast<const uint2*>(o);
    } else if (g < 331776) {
        const int idx = (g - 327680) * 4;
        const float4 v = *reinterpret_cast<const float4*>(Dw + idx);
        u16 o[4] = { f2bf(v.x), f2bf(v.y), f2bf(v.z), f2bf(v.w) };
        *reinterpret_cast<uint2*>(dw16 + idx) = *reinterpret_cast<const uint2*>(o);
    } else if (g < 339968) {
        const int lin0 = (g - 331776) * 4;
        #pragma unroll
        for (int t = 0; t < 4; ++t) {
            const int l = lin0 + t;
            const int bb = l >> 10, rem = l & 1023, i = rem >> 5, j = rem & 31;
            // diagT[b][i][j] = Bs[32b+j, 32b+i] for j>i (update weight from unit i to unit j)
            diagT[l] = (j > i) ? Bs[(size_t)(bb * 32 + j) * 1024 + (bb * 32 + i)] : 0.0f;
        }
    }
}

// ---------------- main: blocked triangular recurrence + output GEMM ----------------
// 512 workgroups x 128 threads (2 waves), 16 batch rows per workgroup -> 2 wgs/CU.
__global__ __launch_bounds__(128) void ren_main(
    const float* __restrict__ u,
    const u16* __restrict__ bs16, const u16* __restrict__ bw16,
    const u16* __restrict__ ds16, const u16* __restrict__ dw16,
    const float* __restrict__ diagT,
    float* __restrict__ out)
{
    __shared__ __align__(16) u16  sh_S[16 * SROW];   // s history, bf16 [16 rows][1024+pad]
    __shared__ float sh_acc[16 * 33];                // pre-activation exchange tile
    __shared__ __align__(16) float sh_dT[2][1024];   // double-buffered diag block (f32)

    const int tid  = threadIdx.x;
    const int wave = tid >> 6;             // 0,1 -> n-tile within the 32-unit block
    const int lane = tid & 63;
    const int ntw  = wave;
    const int lr   = lane & 15;
    const int lk8  = (lane >> 4) << 3;     // k offset of this lane's 8 contiguous elems
    const int row0 = blockIdx.x << 4;      // 16 batch rows per workgroup

    // u A-fragments for the 16 batch rows (k = 0..127), kept in registers
    bfrag fu[4];
    {
        const float* up = u + (size_t)(row0 + lr) * 128 + lk8;
        #pragma unroll
        for (int kk = 0; kk < 4; ++kk) {
            float4 a = *reinterpret_cast<const float4*>(up + kk * 32);
            float4 c = *reinterpret_cast<const float4*>(up + kk * 32 + 4);
            bfrag f;
            f[0] = (short)f2bf(a.x); f[1] = (short)f2bf(a.y);
            f[2] = (short)f2bf(a.z); f[3] = (short)f2bf(a.w);
            f[4] = (short)f2bf(c.x); f[5] = (short)f2bf(c.y);
            f[6] = (short)f2bf(c.z); f[7] = (short)f2bf(c.w);
            fu[kk] = f;
        }
    }

    // stage dT block 0 (consumed after the first barrier)
    {
        const float4* g = reinterpret_cast<const float4*>(diagT + tid * 8);
        float4 a = g[0], c = g[1];
        *reinterpret_cast<float4*>(&sh_dT[0][tid * 8])     = a;
        *reinterpret_cast<float4*>(&sh_dT[0][tid * 8 + 4]) = c;
    }

    for (int b = 0; b < 32; ++b) {
        const int nb = b + 1;
        // issue next dT block's global loads early; LDS writes after the GEMM
        float4 st0, st1;
        if (nb < 32) {
            const float4* g = reinterpret_cast<const float4*>(diagT + (nb << 10) + tid * 8);
            st0 = g[0]; st1 = g[1];
        }

        // ---- GEMM phase: acc[16,32] = u @ B_w[blk]^T + s_hist @ Bs[blk, :32b]^T ----
        f32x4 acc = {0.f, 0.f, 0.f, 0.f};
        const int ng = (b << 5) + (ntw << 4) + lr;     // global hid unit (weight row)

        const u16* bwp = bw16 + ng * 128 + lk8;
        #pragma unroll
        for (int kk = 0; kk < 4; ++kk) {
            bfrag bf = *reinterpret_cast<const bfrag*>(bwp + kk * 32);
            acc = __builtin_amdgcn_mfma_f32_16x16x32_bf16(fu[kk], bf, acc, 0, 0, 0);
        }

        const u16* bsp = bs16 + (size_t)ng * 1024 + lk8;
        const u16* ssp = sh_S + lr * SROW + lk8;
        #pragma unroll 8
        for (int kc = 0; kc < b; ++kc) {
            bfrag af = *reinterpret_cast<const bfrag*>(ssp + (kc << 5));
            bfrag bf = *reinterpret_cast<const bfrag*>(bsp + (kc << 5));
            acc = __builtin_amdgcn_mfma_f32_16x16x32_bf16(af, bf, acc, 0, 0, 0);
        }

        if (nb < 32) {
            *reinterpret_cast<float4*>(&sh_dT[nb & 1][tid * 8])     = st0;
            *reinterpret_cast<float4*>(&sh_dT[nb & 1][tid * 8 + 4]) = st1;
        }

        {   // C/D layout: col = lane&15, row = (lane>>4)*4 + reg
            const int m = (lane >> 4) << 2;
            const int c = (ntw << 4) + lr;
            #pragma unroll
            for (int rr = 0; rr < 4; ++rr)
                sh_acc[(m + rr) * 33 + c] = acc[rr];
        }
        __syncthreads();

        // ---- serial phase: 32 in-block steps, thread r owns batch row r ----
        if (tid < 16) {
            float part[32];
            #pragma unroll
            for (int j = 0; j < 32; ++j) part[j] = sh_acc[tid * 33 + j];
            const float4* dT4 = reinterpret_cast<const float4*>(&sh_dT[b & 1][0]);
            u16* srow = sh_S + tid * SROW + (b << 5);
            #pragma unroll
            for (int i = 0; i < 32; ++i) {
                float s = fast_tanh(part[i]);
                srow[i] = f2bf(s);
                #pragma unroll
                for (int q = (i + 1) >> 2; q < 8; ++q) {
                    float4 w = dT4[i * 8 + q];   // uniform address -> LDS broadcast
                    if (4 * q + 0 > i) part[4 * q + 0] = __builtin_fmaf(w.x, s, part[4 * q + 0]);
                    if (4 * q + 1 > i) part[4 * q + 1] = __builtin_fmaf(w.y, s, part[4 * q + 1]);
                    if (4 * q + 2 > i) part[4 * q + 2] = __builtin_fmaf(w.z, s, part[4 * q + 2]);
                    if (4 * q + 3 > i) part[4 * q + 3] = __builtin_fmaf(w.w, s, part[4 * q + 3]);
                }
            }
        }
        __syncthreads();
    }

    // ---- epilogue: y = s @ Ds_w^T + u @ D_w^T  (16 x 128 per workgroup) ----
    f32x4 accy[4];
    #pragma unroll
    for (int t = 0; t < 4; ++t) accy[t] = (f32x4){0.f, 0.f, 0.f, 0.f};

    const u16* ssp = sh_S + lr * SROW + lk8;
    #pragma unroll 4
    for (int kc = 0; kc < 32; ++kc) {
        bfrag af = *reinterpret_cast<const bfrag*>(ssp + (kc << 5));
        #pragma unroll
        for (int t = 0; t < 4; ++t) {
            const int n = ((ntw << 2) + t) * 16 + lr;
            bfrag bf = *reinterpret_cast<const bfrag*>(ds16 + (size_t)n * 1024 + (kc << 5) + lk8);
            accy[t] = __builtin_amdgcn_mfma_f32_16x16x32_bf16(af, bf, accy[t], 0, 0, 0);
        }
    }
    #pragma unroll
    for (int kk = 0; kk < 4; ++kk) {
        #pragma unroll
        for (int t = 0; t < 4; ++t) {
            const int n = ((ntw << 2) + t) * 16 + lr;
            bfrag bf = *reinterpret_cast<const bfrag*>(dw16 + n * 128 + (kk << 5) + lk8);
            accy[t] = __builtin_amdgcn_mfma_f32_16x16x32_bf16(fu[kk], bf, accy[t], 0, 0, 0);
        }
    }

    {
        const int mbase = row0 + ((lane >> 4) << 2);
        #pragma unroll
        for (int t = 0; t < 4; ++t) {
            const int n = ((ntw << 2) + t) * 16 + lr;
            #pragma unroll
            for (int rr = 0; rr < 4; ++rr)
                out[(size_t)(mbase + rr) * 128 + n] = accy[t][rr];
        }
    }
}

extern "C" void kernel_launch(void* const* d_in, const int* in_sizes, int n_in,
                              void* d_out, int out_size, void* d_ws, size_t ws_size,
                              hipStream_t stream)
{
    const float* u  = (const float*)d_in[0];   // [8192,128]
    const float* Bw = (const float*)d_in[1];   // [1024,128]
    const float* Bs = (const float*)d_in[2];   // [1024,1024]
    const float* Ds = (const float*)d_in[3];   // [128,1024]
    const float* Dw = (const float*)d_in[4];   // [128,128]
    float* out = (float*)d_out;

    u16* bs16 = (u16*)d_ws;                    // 1024*1024 bf16
    u16* bw16 = bs16 + 1024 * 1024;            // 1024*128
    u16* ds16 = bw16 + 1024 * 128;             // 128*1024
    u16* dw16 = ds16 + 128 * 1024;             // 128*128
    float* diagT = (float*)(dw16 + 128 * 128); // 32*32*32 f32

    ren_prologue<<<1328, 256, 0, stream>>>(Bs, Bw, Ds, Dw, bs16, bw16, ds16, dw16, diagT);
    ren_main<<<512, 128, 0, stream>>>(u, bs16, bw16, ds16, dw16, diagT, out);
}

// Round 3
// 191.865 us; speedup vs baseline: 1.6185x; 1.3476x over previous
//
#include <hip/hip_runtime.h>

typedef unsigned short u16;
typedef __attribute__((ext_vector_type(8))) short bfrag;   // 8 x bf16
typedef __attribute__((ext_vector_type(4))) float f32x4;

#define SROW 1032   // padded LDS row stride (bf16 elems): 2064 B, 16B-aligned

__device__ __forceinline__ u16 f2bf(float x) {
    unsigned int v = __float_as_uint(x);
    return (u16)((v + 0x7FFFu + ((v >> 16) & 1u)) >> 16);   // RNE
}

__device__ __forceinline__ float fast_tanh(float x) {
    float e  = __builtin_amdgcn_exp2f(__builtin_fabsf(x) * -2.885390081777927f);
    float r  = (1.0f - e) * __builtin_amdgcn_rcpf(1.0f + e);
    return __builtin_copysignf(r, x);
}

// ---------------- prologue: bf16 conversions + diag-block transpose ----------------
__global__ void ren_prologue(const float* __restrict__ Bs, const float* __restrict__ Bw,
                             const float* __restrict__ Ds, const float* __restrict__ Dw,
                             u16* __restrict__ bs16, u16* __restrict__ bw16,
                             u16* __restrict__ ds16, u16* __restrict__ dw16,
                             float* __restrict__ diagT)
{
    const int g = blockIdx.x * 256 + threadIdx.x;
    if (g < 262144) {
        const int idx = g * 4;
        const int i = idx >> 10, j = idx & 1023;
        const float4 v = *reinterpret_cast<const float4*>(Bs + idx);
        u16 o[4];
        o[0] = (j + 0 < i) ? f2bf(v.x) : (u16)0;
        o[1] = (j + 1 < i) ? f2bf(v.y) : (u16)0;
        o[2] = (j + 2 < i) ? f2bf(v.z) : (u16)0;
        o[3] = (j + 3 < i) ? f2bf(v.w) : (u16)0;
        *reinterpret_cast<uint2*>(bs16 + idx) = *reinterpret_cast<const uint2*>(o);
    } else if (g < 294912) {
        const int idx = (g - 262144) * 4;
        const float4 v = *reinterpret_cast<const float4*>(Bw + idx);
        u16 o[4] = { f2bf(v.x), f2bf(v.y), f2bf(v.z), f2bf(v.w) };
        *reinterpret_cast<uint2*>(bw16 + idx) = *reinterpret_cast<const uint2*>(o);
    } else if (g < 327680) {
        const int idx = (g - 294912) * 4;
        const float4 v = *reinterpret_cast<const float4*>(Ds + idx);
        u16 o[4] = { f2bf(v.x), f2bf(v.y), f2bf(v.z), f2bf(v.w) };
        *reinterpret_cast<uint2*>(ds16 + idx) = *reinterpret_cast<const uint2*>(o);
    } else if (g < 331776) {
        const int idx = (g - 327680) * 4;
        const float4 v = *reinterpret_cast<const float4*>(Dw + idx);
        u16 o[4] = { f2bf(v.x), f2bf(v.y), f2bf(v.z), f2bf(v.w) };
        *reinterpret_cast<uint2*>(dw16 + idx) = *reinterpret_cast<const uint2*>(o);
    } else if (g < 339968) {
        const int lin0 = (g - 331776) * 4;
        #pragma unroll
        for (int t = 0; t < 4; ++t) {
            const int l = lin0 + t;
            const int bb = l >> 10, rem = l & 1023, i = rem >> 5, j = rem & 31;
            // diagT[b][i][j] = Bs[32b+j, 32b+i] for j>i (weight from unit i to unit j)
            diagT[l] = (j > i) ? Bs[(size_t)(bb * 32 + j) * 1024 + (bb * 32 + i)] : 0.0f;
        }
    }
}

// ---------------- main: pipelined triangular recurrence ----------------
// 256 wgs x 192 threads. 32 batch rows per wg. Waves 0,1: GEMM producers
// (m-tile = wave). Wave 2: serial consumer (lane = batch row).
__global__ __launch_bounds__(192) void ren_main(
    const float* __restrict__ u,
    const u16* __restrict__ bs16, const u16* __restrict__ bw16,
    const u16* __restrict__ ds16, const u16* __restrict__ dw16,
    const float* __restrict__ diagT,
    float* __restrict__ out)
{
    __shared__ __align__(16) u16   sh_S[32 * SROW];    // s history bf16 [32][1024+pad]
    __shared__ __align__(16) float sh_acc[32 * 36];    // pre-activation tile [32][36]
    __shared__ __align__(16) float sh_dT[2][1024];     // dbuf diag block f32 [32][32]

    const int tid  = threadIdx.x;
    const int wave = tid >> 6;
    const int lane = tid & 63;
    const int mt   = wave;                 // m-tile for GEMM waves
    const int lr   = lane & 15;
    const int lk8  = (lane >> 4) << 3;
    const int row0 = blockIdx.x << 5;      // 32 batch rows per wg

    bfrag fu[4];                           // u A-frags (GEMM waves only)
    f32x4 accA0, accA1;                    // next-block partial accumulators

    if (wave < 2) {
        const float* up = u + (size_t)(row0 + mt * 16 + lr) * 128 + lk8;
        #pragma unroll
        for (int kk = 0; kk < 4; ++kk) {
            float4 a = *reinterpret_cast<const float4*>(up + kk * 32);
            float4 c = *reinterpret_cast<const float4*>(up + kk * 32 + 4);
            bfrag f;
            f[0] = (short)f2bf(a.x); f[1] = (short)f2bf(a.y);
            f[2] = (short)f2bf(a.z); f[3] = (short)f2bf(a.w);
            f[4] = (short)f2bf(c.x); f[5] = (short)f2bf(c.y);
            f[6] = (short)f2bf(c.z); f[7] = (short)f2bf(c.w);
            fu[kk] = f;
        }
        // stage dT block 0
        {
            const float4* g = reinterpret_cast<const float4*>(diagT + tid * 8);
            float4 a = g[0], c = g[1];
            *reinterpret_cast<float4*>(&sh_dT[0][tid * 8])     = a;
            *reinterpret_cast<float4*>(&sh_dT[0][tid * 8 + 4]) = c;
        }
        // block 0 pre-activations = Bu only
        accA0 = (f32x4){0.f,0.f,0.f,0.f}; accA1 = (f32x4){0.f,0.f,0.f,0.f};
        const u16* p0 = bw16 + (size_t)(lr)      * 128 + lk8;
        const u16* p1 = bw16 + (size_t)(16 + lr) * 128 + lk8;
        #pragma unroll
        for (int kk = 0; kk < 4; ++kk) {
            accA0 = __builtin_amdgcn_mfma_f32_16x16x32_bf16(fu[kk], *reinterpret_cast<const bfrag*>(p0 + kk * 32), accA0, 0, 0, 0);
            accA1 = __builtin_amdgcn_mfma_f32_16x16x32_bf16(fu[kk], *reinterpret_cast<const bfrag*>(p1 + kk * 32), accA1, 0, 0, 0);
        }
        const int m = (mt << 4) + ((lane >> 4) << 2);
        #pragma unroll
        for (int rr = 0; rr < 4; ++rr) {
            sh_acc[(m + rr) * 36 + lr]      = accA0[rr];
            sh_acc[(m + rr) * 36 + 16 + lr] = accA1[rr];
        }
    }
    __syncthreads();

    for (int b = 0; b < 32; ++b) {
        if (wave == 2) {
            // ---------- serial consumer: 32 steps for block b ----------
            if (lane < 32) {
                float part[32];
                const float* accr = sh_acc + lane * 36;
                #pragma unroll
                for (int q = 0; q < 8; ++q) {
                    float4 v = reinterpret_cast<const float4*>(accr)[q];
                    part[4*q+0] = v.x; part[4*q+1] = v.y; part[4*q+2] = v.z; part[4*q+3] = v.w;
                }
                const float* dT = &sh_dT[b & 1][0];
                float4 w0[8], w1[8];
                #pragma unroll
                for (int q = 0; q < 8; ++q) w0[q] = reinterpret_cast<const float4*>(dT)[q];        // row 0
                #pragma unroll
                for (int q = 0; q < 8; ++q) w1[q] = reinterpret_cast<const float4*>(dT + 32)[q];   // row 1
                u16 sv[32];
                #pragma unroll
                for (int i = 0; i < 32; ++i) {
                    float s = fast_tanh(part[i]);
                    sv[i] = f2bf(s);
                    float4 nw[8];
                    if (i < 30) {          // prefetch row i+2 (2-deep)
                        #pragma unroll
                        for (int q = (i + 3) >> 2; q < 8; ++q)
                            nw[q] = reinterpret_cast<const float4*>(dT + ((i + 2) << 5))[q];
                    }
                    #pragma unroll
                    for (int q = (i + 1) >> 2; q < 8; ++q) {
                        if (4*q+0 > i) part[4*q+0] = __builtin_fmaf(w0[q].x, s, part[4*q+0]);
                        if (4*q+1 > i) part[4*q+1] = __builtin_fmaf(w0[q].y, s, part[4*q+1]);
                        if (4*q+2 > i) part[4*q+2] = __builtin_fmaf(w0[q].z, s, part[4*q+2]);
                        if (4*q+3 > i) part[4*q+3] = __builtin_fmaf(w0[q].w, s, part[4*q+3]);
                    }
                    #pragma unroll
                    for (int q = 0; q < 8; ++q) { w0[q] = w1[q]; w1[q] = nw[q]; }
                }
                // publish s_b: pack 32 bf16 -> 4 x b128 writes
                u16* srow = sh_S + lane * SROW + (b << 5);
                #pragma unroll
                for (int c = 0; c < 4; ++c) {
                    uint4 pk;
                    pk.x = (unsigned)sv[8*c+0] | ((unsigned)sv[8*c+1] << 16);
                    pk.y = (unsigned)sv[8*c+2] | ((unsigned)sv[8*c+3] << 16);
                    pk.z = (unsigned)sv[8*c+4] | ((unsigned)sv[8*c+5] << 16);
                    pk.w = (unsigned)sv[8*c+6] | ((unsigned)sv[8*c+7] << 16);
                    *reinterpret_cast<uint4*>(srow + 8 * c) = pk;
                }
            }
        } else if (b < 31) {
            // ---------- GEMM producers: partial for block b+1 (kc < b) ----------
            const int nb = b + 1;
            const float4* g = reinterpret_cast<const float4*>(diagT + (nb << 10) + tid * 8);
            float4 st0 = g[0], st1 = g[1];

            accA0 = (f32x4){0.f,0.f,0.f,0.f}; accA1 = (f32x4){0.f,0.f,0.f,0.f};
            const u16* p0 = bw16 + (size_t)((nb << 5) + lr)      * 128 + lk8;
            const u16* p1 = bw16 + (size_t)((nb << 5) + 16 + lr) * 128 + lk8;
            #pragma unroll
            for (int kk = 0; kk < 4; ++kk) {
                accA0 = __builtin_amdgcn_mfma_f32_16x16x32_bf16(fu[kk], *reinterpret_cast<const bfrag*>(p0 + kk * 32), accA0, 0, 0, 0);
                accA1 = __builtin_amdgcn_mfma_f32_16x16x32_bf16(fu[kk], *reinterpret_cast<const bfrag*>(p1 + kk * 32), accA1, 0, 0, 0);
            }
            const u16* bsp0 = bs16 + (size_t)((nb << 5) + lr)      * 1024 + lk8;
            const u16* bsp1 = bs16 + (size_t)((nb << 5) + 16 + lr) * 1024 + lk8;
            const u16* ssp  = sh_S + ((mt << 4) + lr) * SROW + lk8;
            #pragma unroll 8
            for (int kc = 0; kc < b; ++kc) {
                bfrag af = *reinterpret_cast<const bfrag*>(ssp + (kc << 5));
                accA0 = __builtin_amdgcn_mfma_f32_16x16x32_bf16(af, *reinterpret_cast<const bfrag*>(bsp0 + (kc << 5)), accA0, 0, 0, 0);
                accA1 = __builtin_amdgcn_mfma_f32_16x16x32_bf16(af, *reinterpret_cast<const bfrag*>(bsp1 + (kc << 5)), accA1, 0, 0, 0);
            }
            // land staged dT[b+1]
            *reinterpret_cast<float4*>(&sh_dT[nb & 1][tid * 8])     = st0;
            *reinterpret_cast<float4*>(&sh_dT[nb & 1][tid * 8 + 4]) = st1;
        }
        __syncthreads();   // s_b visible; partials done

        if (wave < 2 && b < 31) {
            // ---------- finish block b+1 with the fresh s_b k-slice ----------
            const int nb = b + 1;
            const u16* bsp0 = bs16 + (size_t)((nb << 5) + lr)      * 1024 + lk8;
            const u16* bsp1 = bs16 + (size_t)((nb << 5) + 16 + lr) * 1024 + lk8;
            const u16* ssp  = sh_S + ((mt << 4) + lr) * SROW + lk8;
            bfrag af = *reinterpret_cast<const bfrag*>(ssp + (b << 5));
            accA0 = __builtin_amdgcn_mfma_f32_16x16x32_bf16(af, *reinterpret_cast<const bfrag*>(bsp0 + (b << 5)), accA0, 0, 0, 0);
            accA1 = __builtin_amdgcn_mfma_f32_16x16x32_bf16(af, *reinterpret_cast<const bfrag*>(bsp1 + (b << 5)), accA1, 0, 0, 0);
            const int m = (mt << 4) + ((lane >> 4) << 2);
            #pragma unroll
            for (int rr = 0; rr < 4; ++rr) {
                sh_acc[(m + rr) * 36 + lr]      = accA0[rr];
                sh_acc[(m + rr) * 36 + 16 + lr] = accA1[rr];
            }
        }
        __syncthreads();   // sh_acc ready for serial(b+1)
    }

    if (wave >= 2) return;

    // ---------------- epilogue: y = s @ Ds^T + u @ D^T ----------------
    f32x4 ey[8];
    #pragma unroll
    for (int t = 0; t < 8; ++t) ey[t] = (f32x4){0.f,0.f,0.f,0.f};

    const u16* ssp = sh_S + ((mt << 4) + lr) * SROW + lk8;
    #pragma unroll 2
    for (int kc = 0; kc < 32; ++kc) {
        bfrag af = *reinterpret_cast<const bfrag*>(ssp + (kc << 5));
        #pragma unroll
        for (int t = 0; t < 8; ++t) {
            bfrag bf = *reinterpret_cast<const bfrag*>(ds16 + (size_t)(t * 16 + lr) * 1024 + (kc << 5) + lk8);
            ey[t] = __builtin_amdgcn_mfma_f32_16x16x32_bf16(af, bf, ey[t], 0, 0, 0);
        }
    }
    #pragma unroll
    for (int kk = 0; kk < 4; ++kk) {
        #pragma unroll
        for (int t = 0; t < 8; ++t) {
            bfrag bf = *reinterpret_cast<const bfrag*>(dw16 + (t * 16 + lr) * 128 + (kk << 5) + lk8);
            ey[t] = __builtin_amdgcn_mfma_f32_16x16x32_bf16(fu[kk], bf, ey[t], 0, 0, 0);
        }
    }
    {
        const int mbase = row0 + (mt << 4) + ((lane >> 4) << 2);
        #pragma unroll
        for (int t = 0; t < 8; ++t) {
            #pragma unroll
            for (int rr = 0; rr < 4; ++rr)
                out[(size_t)(mbase + rr) * 128 + t * 16 + lr] = ey[t][rr];
        }
    }
}

extern "C" void kernel_launch(void* const* d_in, const int* in_sizes, int n_in,
                              void* d_out, int out_size, void* d_ws, size_t ws_size,
                              hipStream_t stream)
{
    const float* u  = (const float*)d_in[0];   // [8192,128]
    const float* Bw = (const float*)d_in[1];   // [1024,128]
    const float* Bs = (const float*)d_in[2];   // [1024,1024]
    const float* Ds = (const float*)d_in[3];   // [128,1024]
    const float* Dw = (const float*)d_in[4];   // [128,128]
    float* out = (float*)d_out;

    u16* bs16 = (u16*)d_ws;                    // 1024*1024 bf16
    u16* bw16 = bs16 + 1024 * 1024;            // 1024*128
    u16* ds16 = bw16 + 1024 * 128;             // 128*1024
    u16* dw16 = ds16 + 128 * 1024;             // 128*128
    float* diagT = (float*)(dw16 + 128 * 128); // 32*32*32 f32

    ren_prologue<<<1328, 256, 0, stream>>>(Bs, Bw, Ds, Dw, bs16, bw16, ds16, dw16, diagT);
    ren_main<<<256, 192, 0, stream>>>(u, bs16, bw16, ds16, dw16, diagT, out);
}

// Round 4
// 190.004 us; speedup vs baseline: 1.6344x; 1.0098x over previous
//
#include <hip/hip_runtime.h>

typedef unsigned short u16;
typedef __attribute__((ext_vector_type(8))) short bfrag;   // 8 x bf16
typedef __attribute__((ext_vector_type(4))) float f32x4;

#define SROW 1032   // padded LDS row stride (bf16 elems): 2064 B, 16B-aligned

__device__ __forceinline__ u16 f2bf(float x) {
    unsigned int v = __float_as_uint(x);
    return (u16)((v + 0x7FFFu + ((v >> 16) & 1u)) >> 16);   // RNE
}

// tanh(x) = 1 - 2/(e^{2x}+1): 5 VALU ops, no fabs/copysign; inf-safe.
__device__ __forceinline__ float fast_tanh(float x) {
    float e = __builtin_amdgcn_exp2f(x * 2.885390081777927f);   // e^{2x}
    return __builtin_fmaf(-2.0f, __builtin_amdgcn_rcpf(e + 1.0f), 1.0f);
}

// ---------------- prologue: bf16 conversions + diag-block transpose ----------------
__global__ void ren_prologue(const float* __restrict__ Bs, const float* __restrict__ Bw,
                             const float* __restrict__ Ds, const float* __restrict__ Dw,
                             u16* __restrict__ bs16, u16* __restrict__ bw16,
                             u16* __restrict__ ds16, u16* __restrict__ dw16,
                             float* __restrict__ diagT)
{
    const int g = blockIdx.x * 256 + threadIdx.x;
    if (g < 262144) {
        const int idx = g * 4;
        const int i = idx >> 10, j = idx & 1023;
        const float4 v = *reinterpret_cast<const float4*>(Bs + idx);
        u16 o[4];
        o[0] = (j + 0 < i) ? f2bf(v.x) : (u16)0;
        o[1] = (j + 1 < i) ? f2bf(v.y) : (u16)0;
        o[2] = (j + 2 < i) ? f2bf(v.z) : (u16)0;
        o[3] = (j + 3 < i) ? f2bf(v.w) : (u16)0;
        *reinterpret_cast<uint2*>(bs16 + idx) = *reinterpret_cast<const uint2*>(o);
    } else if (g < 294912) {
        const int idx = (g - 262144) * 4;
        const float4 v = *reinterpret_cast<const float4*>(Bw + idx);
        u16 o[4] = { f2bf(v.x), f2bf(v.y), f2bf(v.z), f2bf(v.w) };
        *reinterpret_cast<uint2*>(bw16 + idx) = *reinterpret_cast<const uint2*>(o);
    } else if (g < 327680) {
        const int idx = (g - 294912) * 4;
        const float4 v = *reinterpret_cast<const float4*>(Ds + idx);
        u16 o[4] = { f2bf(v.x), f2bf(v.y), f2bf(v.z), f2bf(v.w) };
        *reinterpret_cast<uint2*>(ds16 + idx) = *reinterpret_cast<const uint2*>(o);
    } else if (g < 331776) {
        const int idx = (g - 327680) * 4;
        const float4 v = *reinterpret_cast<const float4*>(Dw + idx);
        u16 o[4] = { f2bf(v.x), f2bf(v.y), f2bf(v.z), f2bf(v.w) };
        *reinterpret_cast<uint2*>(dw16 + idx) = *reinterpret_cast<const uint2*>(o);
    } else if (g < 339968) {
        const int lin0 = (g - 331776) * 4;
        #pragma unroll
        for (int t = 0; t < 4; ++t) {
            const int l = lin0 + t;
            const int bb = l >> 10, rem = l & 1023, i = rem >> 5, j = rem & 31;
            // diagT[b][i][j] = Bs[32b+j, 32b+i] for j>i (weight from unit i to unit j)
            diagT[l] = (j > i) ? Bs[(size_t)(bb * 32 + j) * 1024 + (bb * 32 + i)] : 0.0f;
        }
    }
}

// ---------------- main: pipelined triangular recurrence ----------------
// 256 wgs x 192 threads. 32 batch rows per wg. Waves 0,1: GEMM producers
// (m-tile = wave). Wave 2: serial consumer (lane = batch row).
__global__ __launch_bounds__(192) void ren_main(
    const float* __restrict__ u,
    const u16* __restrict__ bs16, const u16* __restrict__ bw16,
    const u16* __restrict__ ds16, const u16* __restrict__ dw16,
    const float* __restrict__ diagT,
    float* __restrict__ out)
{
    __shared__ __align__(16) u16   sh_S[32 * SROW];    // s history bf16 [32][1024+pad]
    __shared__ __align__(16) float sh_acc[32 * 36];    // pre-activation tile [32][36]
    __shared__ __align__(16) float sh_dT[2][1024];     // dbuf diag block f32 [32][32]

    const int tid  = threadIdx.x;
    const int wave = tid >> 6;
    const int lane = tid & 63;
    const int mt   = wave;                 // m-tile for GEMM waves
    const int lr   = lane & 15;
    const int lk8  = (lane >> 4) << 3;
    const int row0 = blockIdx.x << 5;      // 32 batch rows per wg

    bfrag fu[4];                           // u A-frags (GEMM waves only)
    f32x4 accA0, accA1;                    // next-block partial accumulators

    if (wave < 2) {
        const float* up = u + (size_t)(row0 + mt * 16 + lr) * 128 + lk8;
        #pragma unroll
        for (int kk = 0; kk < 4; ++kk) {
            float4 a = *reinterpret_cast<const float4*>(up + kk * 32);
            float4 c = *reinterpret_cast<const float4*>(up + kk * 32 + 4);
            bfrag f;
            f[0] = (short)f2bf(a.x); f[1] = (short)f2bf(a.y);
            f[2] = (short)f2bf(a.z); f[3] = (short)f2bf(a.w);
            f[4] = (short)f2bf(c.x); f[5] = (short)f2bf(c.y);
            f[6] = (short)f2bf(c.z); f[7] = (short)f2bf(c.w);
            fu[kk] = f;
        }
        // stage dT block 0
        {
            const float4* g = reinterpret_cast<const float4*>(diagT + tid * 8);
            float4 a = g[0], c = g[1];
            *reinterpret_cast<float4*>(&sh_dT[0][tid * 8])     = a;
            *reinterpret_cast<float4*>(&sh_dT[0][tid * 8 + 4]) = c;
        }
        // block 0 pre-activations = Bu only
        accA0 = (f32x4){0.f,0.f,0.f,0.f}; accA1 = (f32x4){0.f,0.f,0.f,0.f};
        const u16* p0 = bw16 + (size_t)(lr)      * 128 + lk8;
        const u16* p1 = bw16 + (size_t)(16 + lr) * 128 + lk8;
        #pragma unroll
        for (int kk = 0; kk < 4; ++kk) {
            accA0 = __builtin_amdgcn_mfma_f32_16x16x32_bf16(fu[kk], *reinterpret_cast<const bfrag*>(p0 + kk * 32), accA0, 0, 0, 0);
            accA1 = __builtin_amdgcn_mfma_f32_16x16x32_bf16(fu[kk], *reinterpret_cast<const bfrag*>(p1 + kk * 32), accA1, 0, 0, 0);
        }
        const int m = (mt << 4) + ((lane >> 4) << 2);
        #pragma unroll
        for (int rr = 0; rr < 4; ++rr) {
            sh_acc[(m + rr) * 36 + lr]      = accA0[rr];
            sh_acc[(m + rr) * 36 + 16 + lr] = accA1[rr];
        }
    }
    __syncthreads();

    for (int b = 0; b < 32; ++b) {
        if (wave == 2) {
            // ---------- serial consumer: 32 steps for block b ----------
            if (lane < 32) {
                float part[32];
                const float* accr = sh_acc + lane * 36;
                #pragma unroll
                for (int q = 0; q < 8; ++q) {
                    float4 v = reinterpret_cast<const float4*>(accr)[q];
                    part[4*q+0] = v.x; part[4*q+1] = v.y; part[4*q+2] = v.z; part[4*q+3] = v.w;
                }
                const float4* dT4 = reinterpret_cast<const float4*>(&sh_dT[b & 1][0]);
                // rolling 2-deep weight prefetch; all indices compile-time ->
                // pure register renaming, no v_mov shuffle.
                float4 wreg[3][8];
                #pragma unroll
                for (int q = 0; q < 8; ++q) wreg[0][q] = dT4[q];
                #pragma unroll
                for (int q = 0; q < 8; ++q) wreg[1][q] = dT4[8 + q];
                u16* srow = sh_S + lane * SROW + (b << 5);
                u16 sv[8];
                #pragma unroll
                for (int i = 0; i < 32; ++i) {
                    if (i + 2 < 32) {
                        #pragma unroll
                        for (int q = (i + 3) >> 2; q < 8; ++q)
                            wreg[(i + 2) % 3][q] = dT4[((i + 2) << 3) + q];
                    }
                    float s = fast_tanh(part[i]);
                    sv[i & 7] = (u16)((__float_as_uint(s) + 0x8000u) >> 16);
                    if ((i & 7) == 7) {   // flush 8 packed bf16 to LDS
                        uint4 pk;
                        pk.x = (unsigned)sv[0] | ((unsigned)sv[1] << 16);
                        pk.y = (unsigned)sv[2] | ((unsigned)sv[3] << 16);
                        pk.z = (unsigned)sv[4] | ((unsigned)sv[5] << 16);
                        pk.w = (unsigned)sv[6] | ((unsigned)sv[7] << 16);
                        *reinterpret_cast<uint4*>(srow + ((i >> 3) << 3)) = pk;
                    }
                    // weights are zero-padded for j <= i: unconditional fmas are no-ops there
                    #pragma unroll
                    for (int q = (i + 1) >> 2; q < 8; ++q) {
                        float4 w = wreg[i % 3][q];
                        part[4*q+0] = __builtin_fmaf(w.x, s, part[4*q+0]);
                        part[4*q+1] = __builtin_fmaf(w.y, s, part[4*q+1]);
                        part[4*q+2] = __builtin_fmaf(w.z, s, part[4*q+2]);
                        part[4*q+3] = __builtin_fmaf(w.w, s, part[4*q+3]);
                    }
                }
            }
        } else if (b < 31) {
            // ---------- GEMM producers: partial for block b+1 (kc < b) ----------
            const int nb = b + 1;
            const float4* g = reinterpret_cast<const float4*>(diagT + (nb << 10) + tid * 8);
            float4 st0 = g[0], st1 = g[1];

            accA0 = (f32x4){0.f,0.f,0.f,0.f}; accA1 = (f32x4){0.f,0.f,0.f,0.f};
            const u16* p0 = bw16 + (size_t)((nb << 5) + lr)      * 128 + lk8;
            const u16* p1 = bw16 + (size_t)((nb << 5) + 16 + lr) * 128 + lk8;
            #pragma unroll
            for (int kk = 0; kk < 4; ++kk) {
                accA0 = __builtin_amdgcn_mfma_f32_16x16x32_bf16(fu[kk], *reinterpret_cast<const bfrag*>(p0 + kk * 32), accA0, 0, 0, 0);
                accA1 = __builtin_amdgcn_mfma_f32_16x16x32_bf16(fu[kk], *reinterpret_cast<const bfrag*>(p1 + kk * 32), accA1, 0, 0, 0);
            }
            const u16* bsp0 = bs16 + (size_t)((nb << 5) + lr)      * 1024 + lk8;
            const u16* bsp1 = bs16 + (size_t)((nb << 5) + 16 + lr) * 1024 + lk8;
            const u16* ssp  = sh_S + ((mt << 4) + lr) * SROW + lk8;
            #pragma unroll 8
            for (int kc = 0; kc < b; ++kc) {
                bfrag af = *reinterpret_cast<const bfrag*>(ssp + (kc << 5));
                accA0 = __builtin_amdgcn_mfma_f32_16x16x32_bf16(af, *reinterpret_cast<const bfrag*>(bsp0 + (kc << 5)), accA0, 0, 0, 0);
                accA1 = __builtin_amdgcn_mfma_f32_16x16x32_bf16(af, *reinterpret_cast<const bfrag*>(bsp1 + (kc << 5)), accA1, 0, 0, 0);
            }
            // land staged dT[b+1]
            *reinterpret_cast<float4*>(&sh_dT[nb & 1][tid * 8])     = st0;
            *reinterpret_cast<float4*>(&sh_dT[nb & 1][tid * 8 + 4]) = st1;
        }
        __syncthreads();   // s_b visible; partials done

        if (wave < 2 && b < 31) {
            // ---------- finish block b+1 with the fresh s_b k-slice ----------
            const int nb = b + 1;
            const u16* bsp0 = bs16 + (size_t)((nb << 5) + lr)      * 1024 + lk8;
            const u16* bsp1 = bs16 + (size_t)((nb << 5) + 16 + lr) * 1024 + lk8;
            const u16* ssp  = sh_S + ((mt << 4) + lr) * SROW + lk8;
            bfrag af = *reinterpret_cast<const bfrag*>(ssp + (b << 5));
            accA0 = __builtin_amdgcn_mfma_f32_16x16x32_bf16(af, *reinterpret_cast<const bfrag*>(bsp0 + (b << 5)), accA0, 0, 0, 0);
            accA1 = __builtin_amdgcn_mfma_f32_16x16x32_bf16(af, *reinterpret_cast<const bfrag*>(bsp1 + (b << 5)), accA1, 0, 0, 0);
            const int m = (mt << 4) + ((lane >> 4) << 2);
            #pragma unroll
            for (int rr = 0; rr < 4; ++rr) {
                sh_acc[(m + rr) * 36 + lr]      = accA0[rr];
                sh_acc[(m + rr) * 36 + 16 + lr] = accA1[rr];
            }
        }
        __syncthreads();   // sh_acc ready for serial(b+1)
    }

    if (wave >= 2) return;

    // ---------------- epilogue: y = s @ Ds^T + u @ D^T ----------------
    f32x4 ey[8];
    #pragma unroll
    for (int t = 0; t < 8; ++t) ey[t] = (f32x4){0.f,0.f,0.f,0.f};

    const u16* ssp = sh_S + ((mt << 4) + lr) * SROW + lk8;
    #pragma unroll 2
    for (int kc = 0; kc < 32; ++kc) {
        bfrag af = *reinterpret_cast<const bfrag*>(ssp + (kc << 5));
        #pragma unroll
        for (int t = 0; t < 8; ++t) {
            bfrag bf = *reinterpret_cast<const bfrag*>(ds16 + (size_t)(t * 16 + lr) * 1024 + (kc << 5) + lk8);
            ey[t] = __builtin_amdgcn_mfma_f32_16x16x32_bf16(af, bf, ey[t], 0, 0, 0);
        }
    }
    #pragma unroll
    for (int kk = 0; kk < 4; ++kk) {
        #pragma unroll
        for (int t = 0; t < 8; ++t) {
            bfrag bf = *reinterpret_cast<const bfrag*>(dw16 + (t * 16 + lr) * 128 + (kk << 5) + lk8);
            ey[t] = __builtin_amdgcn_mfma_f32_16x16x32_bf16(fu[kk], bf, ey[t], 0, 0, 0);
        }
    }
    {
        const int mbase = row0 + (mt << 4) + ((lane >> 4) << 2);
        #pragma unroll
        for (int t = 0; t < 8; ++t) {
            #pragma unroll
            for (int rr = 0; rr < 4; ++rr)
                out[(size_t)(mbase + rr) * 128 + t * 16 + lr] = ey[t][rr];
        }
    }
}

extern "C" void kernel_launch(void* const* d_in, const int* in_sizes, int n_in,
                              void* d_out, int out_size, void* d_ws, size_t ws_size,
                              hipStream_t stream)
{
    const float* u  = (const float*)d_in[0];   // [8192,128]
    const float* Bw = (const float*)d_in[1];   // [1024,128]
    const float* Bs = (const float*)d_in[2];   // [1024,1024]
    const float* Ds = (const float*)d_in[3];   // [128,1024]
    const float* Dw = (const float*)d_in[4];   // [128,128]
    float* out = (float*)d_out;

    u16* bs16 = (u16*)d_ws;                    // 1024*1024 bf16
    u16* bw16 = bs16 + 1024 * 1024;            // 1024*128
    u16* ds16 = bw16 + 1024 * 128;             // 128*1024
    u16* dw16 = ds16 + 128 * 1024;             // 128*128
    float* diagT = (float*)(dw16 + 128 * 128); // 32*32*32 f32

    ren_prologue<<<1328, 256, 0, stream>>>(Bs, Bw, Ds, Dw, bs16, bw16, ds16, dw16, diagT);
    ren_main<<<256, 192, 0, stream>>>(u, bs16, bw16, ds16, dw16, diagT, out);
}